// Round 1
// baseline (777.516 us; speedup 1.0000x reference)
//
#include <hip/hip_runtime.h>
#include <stdint.h>

typedef float v4f __attribute__((ext_vector_type(4)));
typedef __bf16 v8bf __attribute__((ext_vector_type(8)));
typedef unsigned short v8us __attribute__((ext_vector_type(8)));

#define HALF 1024
#define MTOT 32768
#define NTOT 2048            // doubled: [real cols | imag cols]
#define KTOT 2048            // doubled: [x_r | x_i]
#define OUT_HALF (MTOT * HALF)   // 33554432 elements per output tensor

// fp32 -> bf16, round-to-nearest-even (bit trick, no API dependence)
__device__ __forceinline__ unsigned short f2bf(float f) {
  uint32_t u = __float_as_uint(f);
  u += 0x7fffu + ((u >> 16) & 1u);
  return (unsigned short)(u >> 16);
}

// async global->LDS, 16B per lane; LDS dest is wave-uniform base + lane*16
__device__ __forceinline__ void gl_lds16(const void* g, void* s) {
  __builtin_amdgcn_global_load_lds(
      (const __attribute__((address_space(1))) void*)g,
      (__attribute__((address_space(3))) void*)s, 16, 0, 0);
}

// A2[m, 0:1024] = bf16(x_r[m,:]);  A2[m, 1024:2048] = bf16(x_i[m,:])
__global__ void prep_a(const float* __restrict__ xr, const float* __restrict__ xi,
                       unsigned short* __restrict__ A2) {
  const int t  = blockIdx.x * 256 + threadIdx.x;
  const int e0 = t << 3;               // 8 elements / thread
  const int m  = e0 >> 11;
  const int n  = e0 & 2047;            // 8-aligned; never straddles 1024
  const float* src = (n < HALF) ? (xr + m * HALF + n) : (xi + m * HALF + (n - HALF));
  const float4 f0 = *(const float4*)src;
  const float4 f1 = *(const float4*)(src + 4);
  v8us o;
  o[0] = f2bf(f0.x); o[1] = f2bf(f0.y); o[2] = f2bf(f0.z); o[3] = f2bf(f0.w);
  o[4] = f2bf(f1.x); o[5] = f2bf(f1.y); o[6] = f2bf(f1.z); o[7] = f2bf(f1.w);
  *(v8us*)(A2 + e0) = o;
}

// B3 (2048 x 2048, row-major, reduction contiguous):
//  row j<1024  (real out col k=j):      [ w_real[k,:] | -w_imag[k,:] ]
//  row j>=1024 (imag out col k=j-1024): [ w_imag[k,:] |  w_real[k,:] ]
__global__ void prep_b(const float* __restrict__ wr, const float* __restrict__ wi,
                       unsigned short* __restrict__ B3) {
  const int t  = blockIdx.x * 256 + threadIdx.x;
  const int e0 = t << 3;
  const int j  = e0 >> 11;
  const int n  = e0 & 2047;
  const int k  = j & 1023;
  const int nn = n & 1023;
  const float* src;
  float sgn = 1.0f;
  if (j < HALF) {
    if (n < HALF) { src = wr; } else { src = wi; sgn = -1.0f; }
  } else {
    if (n < HALF) { src = wi; } else { src = wr; }
  }
  src += k * HALF + nn;
  const float4 f0 = *(const float4*)src;
  const float4 f1 = *(const float4*)(src + 4);
  v8us o;
  o[0] = f2bf(sgn * f0.x); o[1] = f2bf(sgn * f0.y);
  o[2] = f2bf(sgn * f0.z); o[3] = f2bf(sgn * f0.w);
  o[4] = f2bf(sgn * f1.x); o[5] = f2bf(sgn * f1.y);
  o[6] = f2bf(sgn * f1.z); o[7] = f2bf(sgn * f1.w);
  *(v8us*)(B3 + e0) = o;
}

// m97-pattern GEMM: C[m,j] = sum_k A2[m,k]*B3[j,k]  (both reduction-contiguous)
// 128x128 block tile, BK=32, 256 threads = 2x2 waves of 64x64,
// mfma_f32_16x16x32_bf16, global_load_lds width=16 staging.
__global__ void __launch_bounds__(256)
gemm_cplx(const unsigned short* __restrict__ A2,
          const unsigned short* __restrict__ B3,
          const float* __restrict__ br, const float* __restrict__ bi,
          float* __restrict__ out) {
  __shared__ unsigned short sA[128 * 32];   // [row m 0..127][k 0..31]
  __shared__ unsigned short sB[128 * 32];   // [row n 0..127][k 0..31]

  const int tid = threadIdx.x;
  const int L   = tid & 63;
  const int w   = tid >> 6;
  const int m0  = blockIdx.y * 128;
  const int n0  = blockIdx.x * 128;

  // staging: issue i in {0,1} per matrix; flat elem = i*2048 + tid*8
  const int srow = tid >> 2;            // 0..63
  const int scol = (tid & 3) * 8;
  const unsigned short* gA0 = A2 + (size_t)(m0 + srow) * KTOT + scol;
  const unsigned short* gA1 = gA0 + (size_t)64 * KTOT;
  const unsigned short* gB0 = B3 + (size_t)(n0 + srow) * KTOT + scol;
  const unsigned short* gB1 = gB0 + (size_t)64 * KTOT;
  unsigned short* sAp = &sA[w * 512];   // HW adds lane*16 bytes (= lane*8 elems)
  unsigned short* sBp = &sB[w * 512];

  // fragment addressing (16x16x32: A[m=lane&15][k=quad*8+j])
  const int quad   = L >> 4;
  const int lr     = L & 15;
  const int m_base = (w >> 1) * 64;
  const int n_base = (w & 1) * 64;
  const unsigned short* fA = &sA[(m_base + lr) * 32 + quad * 8];
  const unsigned short* fB = &sB[(n_base + lr) * 32 + quad * 8];

  v4f acc[4][4];
#pragma unroll
  for (int a = 0; a < 4; ++a)
#pragma unroll
    for (int b = 0; b < 4; ++b)
      acc[a][b] = (v4f){0.f, 0.f, 0.f, 0.f};

  for (int kt = 0; kt < KTOT / 32; ++kt) {
    const int ko = kt * 32;
    __syncthreads();                    // previous iter's readers done
    gl_lds16(gA0 + ko, sAp);
    gl_lds16(gA1 + ko, sAp + 2048);
    gl_lds16(gB0 + ko, sBp);
    gl_lds16(gB1 + ko, sBp + 2048);
    __syncthreads();                    // drains vmcnt: staging visible

    v8bf af[4], bfr[4];
#pragma unroll
    for (int a = 0; a < 4; ++a) af[a] = *(const v8bf*)(fA + a * 16 * 32);
#pragma unroll
    for (int b = 0; b < 4; ++b) bfr[b] = *(const v8bf*)(fB + b * 16 * 32);
#pragma unroll
    for (int a = 0; a < 4; ++a)
#pragma unroll
      for (int b = 0; b < 4; ++b)
        acc[a][b] = __builtin_amdgcn_mfma_f32_16x16x32_bf16(af[a], bfr[b], acc[a][b], 0, 0, 0);
  }

  // epilogue: C/D layout col=lane&15 (n), row=quad*4+reg (m); fuse bias
  const bool is_real = (n0 < HALF);     // block-uniform: BN=128 divides 1024
  float* obase = is_real ? out : (out + OUT_HALF);
  const int cb = n0 + n_base + lr - (is_real ? 0 : HALF);
  float bias[4];
#pragma unroll
  for (int b = 0; b < 4; ++b) {
    const int c = cb + b * 16;
    bias[b] = is_real ? (br[c] - bi[c]) : (br[c] + bi[c]);
  }
#pragma unroll
  for (int a = 0; a < 4; ++a) {
    const int mr = m0 + m_base + a * 16 + quad * 4;
#pragma unroll
    for (int b = 0; b < 4; ++b) {
      float* po = obase + (size_t)mr * HALF + cb + b * 16;
#pragma unroll
      for (int r = 0; r < 4; ++r)
        po[(size_t)r * HALF] = acc[a][b][r] + bias[b];
    }
  }
}

extern "C" void kernel_launch(void* const* d_in, const int* in_sizes, int n_in,
                              void* d_out, int out_size, void* d_ws, size_t ws_size,
                              hipStream_t stream) {
  const float* xr = (const float*)d_in[0];
  const float* xi = (const float*)d_in[1];
  const float* wr = (const float*)d_in[2];
  const float* wi = (const float*)d_in[3];
  const float* br = (const float*)d_in[4];
  const float* bi = (const float*)d_in[5];
  float* out = (float*)d_out;

  const size_t needA = (size_t)MTOT * KTOT * sizeof(unsigned short);  // 134,217,728
  const size_t needB = (size_t)NTOT * KTOT * sizeof(unsigned short);  //   8,388,608
  if (ws_size < needA + needB) {
    // diagnostic: zeroed output => absmax equals |ref|max (~186) => ws too small,
    // distinguishable from a layout bug.
    hipMemsetAsync(d_out, 0, (size_t)out_size * sizeof(float), stream);
    return;
  }
  unsigned short* A2 = (unsigned short*)d_ws;
  unsigned short* B3 = (unsigned short*)((char*)d_ws + needA);

  prep_a<<<(MTOT * KTOT / 8) / 256, 256, 0, stream>>>(xr, xi, A2);   // 32768 blocks
  prep_b<<<(NTOT * KTOT / 8) / 256, 256, 0, stream>>>(wr, wi, B3);   //  2048 blocks
  dim3 grid(NTOT / 128, MTOT / 128);                                  // 16 x 256
  gemm_cplx<<<grid, 256, 0, stream>>>(A2, B3, br, bi, out);
}

// Round 2
// 736.710 us; speedup vs baseline: 1.0554x; 1.0554x over previous
//
#include <hip/hip_runtime.h>
#include <stdint.h>

typedef float v4f __attribute__((ext_vector_type(4)));
typedef __bf16 v8bf __attribute__((ext_vector_type(8)));
typedef unsigned short v8us __attribute__((ext_vector_type(8)));

#define HALF 1024
#define MTOT 32768
#define NTOT 2048            // [real cols | imag cols]
#define KTOT 2048            // [x_r | x_i]
#define BK   64
#define OUT_HALF (MTOT * HALF)

__device__ __forceinline__ unsigned short f2bf(float f) {
  uint32_t u = __float_as_uint(f);
  u += 0x7fffu + ((u >> 16) & 1u);
  return (unsigned short)(u >> 16);
}

__device__ __forceinline__ void gl_lds16(const void* g, void* s) {
  __builtin_amdgcn_global_load_lds(
      (const __attribute__((address_space(1))) void*)g,
      (__attribute__((address_space(3))) void*)s, 16, 0, 0);
}

__global__ void __launch_bounds__(256)
prep_a(const float* __restrict__ xr, const float* __restrict__ xi,
       unsigned short* __restrict__ A2) {
  const int t  = blockIdx.x * 256 + threadIdx.x;
  const int e0 = t << 3;
  const int m  = e0 >> 11;
  const int n  = e0 & 2047;
  const float* src = (n < HALF) ? (xr + m * HALF + n) : (xi + m * HALF + (n - HALF));
  const float4 f0 = *(const float4*)src;
  const float4 f1 = *(const float4*)(src + 4);
  v8us o;
  o[0] = f2bf(f0.x); o[1] = f2bf(f0.y); o[2] = f2bf(f0.z); o[3] = f2bf(f0.w);
  o[4] = f2bf(f1.x); o[5] = f2bf(f1.y); o[6] = f2bf(f1.z); o[7] = f2bf(f1.w);
  *(v8us*)(A2 + e0) = o;
}

// B3 row j<1024: [ w_real[j,:] | -w_imag[j,:] ]; row j>=1024: [ w_imag[k,:] | w_real[k,:] ]
__global__ void __launch_bounds__(256)
prep_b(const float* __restrict__ wr, const float* __restrict__ wi,
       unsigned short* __restrict__ B3) {
  const int t  = blockIdx.x * 256 + threadIdx.x;
  const int e0 = t << 3;
  const int j  = e0 >> 11;
  const int n  = e0 & 2047;
  const int k  = j & 1023;
  const int nn = n & 1023;
  const float* src;
  float sgn = 1.0f;
  if (j < HALF) { if (n < HALF) src = wr; else { src = wi; sgn = -1.0f; } }
  else          { if (n < HALF) src = wi; else   src = wr; }
  src += k * HALF + nn;
  const float4 f0 = *(const float4*)src;
  const float4 f1 = *(const float4*)(src + 4);
  v8us o;
  o[0] = f2bf(sgn * f0.x); o[1] = f2bf(sgn * f0.y);
  o[2] = f2bf(sgn * f0.z); o[3] = f2bf(sgn * f0.w);
  o[4] = f2bf(sgn * f1.x); o[5] = f2bf(sgn * f1.y);
  o[6] = f2bf(sgn * f1.z); o[7] = f2bf(sgn * f1.w);
  *(v8us*)(B3 + e0) = o;
}

// 128x128 tile, BK=64, XOR-swizzled LDS (conflict-free ds_read_b128),
// global_load_lds width-16 staging, XCD-aware block remap, fused bias.
__global__ void __launch_bounds__(256)
gemm_cplx(const unsigned short* __restrict__ A2,
          const unsigned short* __restrict__ B3,
          const float* __restrict__ br, const float* __restrict__ bi,
          float* __restrict__ out) {
  __shared__ unsigned short sA[128 * BK];   // 16 KB, row stride 128B
  __shared__ unsigned short sB[128 * BK];   // 16 KB

  const int tid = threadIdx.x;
  const int L   = tid & 63;
  const int w   = tid >> 6;

  // XCD-aware remap: all 16 N-blocks of one A-stripe land on one XCD (F%8).
  const int F   = blockIdx.y * 16 + blockIdx.x;   // dispatch-order flat id
  const int xcd = F & 7;
  const int j   = F >> 3;                         // 0..511 per XCD
  const int by  = xcd + ((j >> 4) << 3);          // stripes == xcd (mod 8)
  const int bx  = j & 15;
  const int m0  = by * 128;
  const int n0  = bx * 128;

  // staging: 4 issues per matrix; slot s = i*256+tid (16B units)
  // physical chunk p = tid&7; row = i*32 + (tid>>3); logical chunk c = p ^ (row&7)
  const int r0 = tid >> 3;                        // 0..31
  const int c  = (tid & 7) ^ (r0 & 7);            // source-permuted chunk
  const unsigned short* gA = A2 + (size_t)(m0 + r0) * KTOT + c * 8;
  const unsigned short* gB = B3 + (size_t)(n0 + r0) * KTOT + c * 8;
  unsigned short* sAp = &sA[(size_t)w * 64 * 8];  // + i*256*8 per issue
  unsigned short* sBp = &sB[(size_t)w * 64 * 8];

  // fragment addressing: row = base + a*16 + lr; k = kk*32 + quad*8 + j
  // physical offset (shorts) = row*64 + (((kk*4+quad) ^ (lr&7)) * 8)
  const int quad   = L >> 4;
  const int lr     = L & 15;
  const int m_base = (w >> 1) * 64;
  const int n_base = (w & 1) * 64;
  const int sw     = lr & 7;

  v4f acc[4][4];
#pragma unroll
  for (int a = 0; a < 4; ++a)
#pragma unroll
    for (int b = 0; b < 4; ++b)
      acc[a][b] = (v4f){0.f, 0.f, 0.f, 0.f};

  for (int kt = 0; kt < KTOT / BK; ++kt) {
    const int ko = kt * BK;
    __syncthreads();
#pragma unroll
    for (int i = 0; i < 4; ++i)
      gl_lds16(gA + (size_t)i * 32 * KTOT + ko, sAp + i * 256 * 8);
#pragma unroll
    for (int i = 0; i < 4; ++i)
      gl_lds16(gB + (size_t)i * 32 * KTOT + ko, sBp + i * 256 * 8);
    __syncthreads();

#pragma unroll
    for (int kk = 0; kk < 2; ++kk) {
      v8bf af[4], bfr[4];
#pragma unroll
      for (int a = 0; a < 4; ++a) {
        const int row = m_base + a * 16 + lr;
        af[a] = *(const v8bf*)(&sA[row * 64 + (((kk * 4 + quad) ^ sw) * 8)]);
      }
#pragma unroll
      for (int b = 0; b < 4; ++b) {
        const int row = n_base + b * 16 + lr;
        bfr[b] = *(const v8bf*)(&sB[row * 64 + (((kk * 4 + quad) ^ sw) * 8)]);
      }
#pragma unroll
      for (int a = 0; a < 4; ++a)
#pragma unroll
        for (int b = 0; b < 4; ++b)
          acc[a][b] = __builtin_amdgcn_mfma_f32_16x16x32_bf16(af[a], bfr[b], acc[a][b], 0, 0, 0);
    }
  }

  // epilogue: C/D col=lane&15, row=quad*4+reg; fuse bias
  const bool is_real = (n0 < HALF);
  float* obase = is_real ? out : (out + OUT_HALF);
  const int cb = n0 + n_base + lr - (is_real ? 0 : HALF);
  float bias[4];
#pragma unroll
  for (int b = 0; b < 4; ++b) {
    const int col = cb + b * 16;
    bias[b] = is_real ? (br[col] - bi[col]) : (br[col] + bi[col]);
  }
#pragma unroll
  for (int a = 0; a < 4; ++a) {
    const int mr = m0 + m_base + a * 16 + quad * 4;
#pragma unroll
    for (int b = 0; b < 4; ++b) {
      float* po = obase + (size_t)mr * HALF + cb + b * 16;
#pragma unroll
      for (int r = 0; r < 4; ++r)
        po[(size_t)r * HALF] = acc[a][b][r] + bias[b];
    }
  }
}

extern "C" void kernel_launch(void* const* d_in, const int* in_sizes, int n_in,
                              void* d_out, int out_size, void* d_ws, size_t ws_size,
                              hipStream_t stream) {
  const float* xr = (const float*)d_in[0];
  const float* xi = (const float*)d_in[1];
  const float* wr = (const float*)d_in[2];
  const float* wi = (const float*)d_in[3];
  const float* br = (const float*)d_in[4];
  const float* bi = (const float*)d_in[5];
  float* out = (float*)d_out;

  const size_t needA = (size_t)MTOT * KTOT * sizeof(unsigned short);
  const size_t needB = (size_t)NTOT * KTOT * sizeof(unsigned short);
  if (ws_size < needA + needB) {
    hipMemsetAsync(d_out, 0, (size_t)out_size * sizeof(float), stream);
    return;
  }
  unsigned short* A2 = (unsigned short*)d_ws;
  unsigned short* B3 = (unsigned short*)((char*)d_ws + needA);

  prep_a<<<(MTOT * KTOT / 8) / 256, 256, 0, stream>>>(xr, xi, A2);
  prep_b<<<(NTOT * KTOT / 8) / 256, 256, 0, stream>>>(wr, wi, B3);
  dim3 grid(NTOT / 128, MTOT / 128);
  gemm_cplx<<<grid, 256, 0, stream>>>(A2, B3, br, bi, out);
}